// Round 10
// baseline (810.653 us; speedup 1.0000x reference)
//
#include <hip/hip_runtime.h>
#include <hip/hip_fp16.h>
#include <math.h>

#define T_ 128
#define B_ 32
#define D_ 512
#define V_ 128
#define S_ 64
#define N_ 4
#define R_ 64
#define O_ 64

typedef _Float16 h4 __attribute__((ext_vector_type(4)));
typedef _Float16 h8 __attribute__((ext_vector_type(8)));
typedef float f4 __attribute__((ext_vector_type(4)));

__device__ __forceinline__ float fsigm(float x) {
    return __fdividef(1.0f, 1.0f + __expf(-x));
}
__device__ __forceinline__ float ftanh(float x) {
    float e = __expf(2.f * x);
    return 1.f - __fdividef(2.f, e + 1.f);
}

// ---- h8-contiguous fragment layout for [rows][64] f16 operand tiles (k2) ----
__device__ __forceinline__ int fidx(int row, int ks, int g) {
    return row * 64 + ((((ks << 2) | g) ^ (row & 7)) << 3);
}
__device__ __forceinline__ int sidx(int row, int k) {
    int ks = k >> 5, u = (k >> 4) & 1, gg = (k >> 2) & 3, e = k & 3;
    return row * 64 + ((((ks << 2) | gg) ^ (row & 7)) << 3) + (u << 2) + e;
}

// ---- A-fragment LDS layouts for K=512 / K=64 (k1/k3) ----
__device__ __forceinline__ int afi512(int row, int ks, int g) {
    return row * 512 + ((((ks << 2) | g) ^ (row & 7)) << 3);
}
__device__ __forceinline__ int afw512(int row, int k) {
    return row * 512 + (((((k >> 5) << 2) | ((k >> 2) & 3)) ^ (row & 7)) << 3)
         + (((k >> 4) & 1) << 2) + (k & 3);
}
__device__ __forceinline__ int afi64(int row, int ks, int g) {
    return row * 64 + ((((ks << 2) | g) ^ (row & 7)) << 3);
}
__device__ __forceinline__ int afw64(int row, int k) {
    return row * 64 + (((((k >> 5) << 2) | ((k >> 2) & 3)) ^ (row & 7)) << 3)
         + (((k >> 4) & 1) << 2) + (k & 3);
}

// fragment-layout weight segment offsets (halves) within hW
#define OFF_WE    0
#define OFF_WIN   262144
#define OFF_WIN2  294912
#define OFF_WIN3  327680
#define OFF_WIG   335872
#define OFF_WREL3 344064
#define OFF_WM1   348160
#define OFF_WM2   380928
#define OFF_WOUT  643072
#define OFF_WFC   905216
#define HW_TOTAL  970752

// ---------------------------------------------------------------------------
// K0: convert 10 weight matrices to fragment-interleaved fp16 — unchanged
// ---------------------------------------------------------------------------
__global__ __launch_bounds__(256)
void k0_conv(const float* __restrict__ We, const float* __restrict__ Win,
             const float* __restrict__ Win2, const float* __restrict__ Win3,
             const float* __restrict__ Wig, const float* __restrict__ Wrel3,
             const float* __restrict__ Wm1, const float* __restrict__ Wm2,
             const float* __restrict__ Wout, const float* __restrict__ Wfc,
             _Float16* __restrict__ outh)
{
    int idx = blockIdx.x * 256 + threadIdx.x;
    if (idx >= HW_TOTAL) return;
    const float* W; int base, Nn, NT;
    if (idx < OFF_WIN)        { W = We;    base = OFF_WE;    Nn = 512; NT = 32; }
    else if (idx < OFF_WIN2)  { W = Win;   base = OFF_WIN;   Nn = 64;  NT = 4;  }
    else if (idx < OFF_WIN3)  { W = Win2;  base = OFF_WIN2;  Nn = 64;  NT = 4;  }
    else if (idx < OFF_WIG)   { W = Win3;  base = OFF_WIN3;  Nn = 4;   NT = 1;  }
    else if (idx < OFF_WREL3) { W = Wig;   base = OFF_WIG;   Nn = 128; NT = 8;  }
    else if (idx < OFF_WM1)   { W = Wrel3; base = OFF_WREL3; Nn = 64;  NT = 4;  }
    else if (idx < OFF_WM2)   { W = Wm1;   base = OFF_WM1;   Nn = 512; NT = 32; }
    else if (idx < OFF_WOUT)  { W = Wm2;   base = OFF_WM2;   Nn = 512; NT = 32; }
    else if (idx < OFF_WFC)   { W = Wout;  base = OFF_WOUT;  Nn = 512; NT = 32; }
    else                      { W = Wfc;   base = OFF_WFC;   Nn = 128; NT = 8;  }
    int local = idx - base;
    int e = local & 7, fr = local >> 3;
    int l = fr & 63, ctks = fr >> 6;
    int ks = ctks / NT, ct = ctks - ks * NT;
    int col = ct * 16 + (l & 15);
    int k = ks * 32 + ((e >> 2) << 4) + ((l >> 4) << 2) + (e & 3);
    outh[idx] = (col < Nn) ? (_Float16)W[k * Nn + col] : (_Float16)0.f;
}

// ---------------------------------------------------------------------------
// K1: MFMA precompute — unchanged
// ---------------------------------------------------------------------------
__global__ __launch_bounds__(512)
void k1_pre(const int* __restrict__ ids, const float* __restrict__ emb,
            const _Float16* __restrict__ hW,
            const float* __restrict__ be, const float* __restrict__ b_in,
            const float* __restrict__ b_in2, const float* __restrict__ b_in3,
            const float* __restrict__ b_ig,
            float* __restrict__ v_all, float* __restrict__ gIn_all,
            float* __restrict__ w3_all, float* __restrict__ xo_all)
{
    __shared__ __align__(16) _Float16 afE[16 * 512];
    __shared__ __align__(16) _Float16 afS[16 * 512];
    __shared__ __align__(16) _Float16 afV[16 * 64];
    const int tid = threadIdx.x;
    const int wv = tid >> 6, l = tid & 63, li = l & 15, g = l >> 4;
    const int f0 = blockIdx.x * 16;

    const _Float16* WeF   = hW + OFF_WE;
    const _Float16* WinF  = hW + OFF_WIN;
    const _Float16* Win2F = hW + OFF_WIN2;
    const _Float16* Win3F = hW + OFF_WIN3;
    const _Float16* WigF  = hW + OFF_WIG;

#pragma unroll
    for (int row = 0; row < 16; ++row) {
        const int f = f0 + row, t = f >> 5, bb = f & 31;
        const int id = ids[bb * T_ + t];
        afE[afw512(row, tid)] = (_Float16)emb[id * D_ + tid];
    }
    __syncthreads();

    {
        h8 a[16];
#pragma unroll
        for (int ks = 0; ks < 16; ++ks) a[ks] = *(const h8*)&afE[afi512(li, ks, g)];
#pragma unroll
        for (int c4 = 0; c4 < 4; ++c4) {
            const int ct = (wv << 2) + c4;
            const int col = (ct << 4) + li;
            const float bb = be[col];
            f4 acc = {bb, bb, bb, bb};
#pragma unroll
            for (int ks = 0; ks < 16; ++ks)
                acc = __builtin_amdgcn_mfma_f32_16x16x32_f16(
                    a[ks], *(const h8*)&WeF[((ks * 32 + ct) * 64 + l) * 8], acc, 0, 0, 0);
#pragma unroll
            for (int r = 0; r < 4; ++r)
                afS[afw512((g << 2) + r, col)] = (_Float16)acc[r];
        }
    }
    __syncthreads();

    h8 s[16];
#pragma unroll
    for (int ks = 0; ks < 16; ++ks) s[ks] = *(const h8*)&afS[afi512(li, ks, g)];
    if (wv < 4) {
        const int col = (wv << 4) + li;
        const float bb = b_in[col];
        f4 acc = {bb, bb, bb, bb};
#pragma unroll
        for (int ks = 0; ks < 16; ++ks)
            acc = __builtin_amdgcn_mfma_f32_16x16x32_f16(
                s[ks], *(const h8*)&WinF[((ks * 4 + wv) * 64 + l) * 8], acc, 0, 0, 0);
#pragma unroll
        for (int r = 0; r < 4; ++r) {
            const int row = (g << 2) + r;
            v_all[(f0 + row) * S_ + col] = acc[r];
            afV[afw64(row, col)] = (_Float16)acc[r];
        }
    } else {
        const int ct = wv - 4;
        const int col = (ct << 4) + li;
        const float bb = b_in2[col];
        f4 acc = {bb, bb, bb, bb};
#pragma unroll
        for (int ks = 0; ks < 16; ++ks)
            acc = __builtin_amdgcn_mfma_f32_16x16x32_f16(
                s[ks], *(const h8*)&Win2F[((ks * 4 + ct) * 64 + l) * 8], acc, 0, 0, 0);
#pragma unroll
        for (int r = 0; r < 4; ++r)
            xo_all[(f0 + (g << 2) + r) * O_ + col] = acc[r];
    }
    __syncthreads();

    if (wv == 0) {
        f4 acc = {0.f, 0.f, 0.f, 0.f};
#pragma unroll
        for (int ks = 0; ks < 16; ++ks)
            acc = __builtin_amdgcn_mfma_f32_16x16x32_f16(
                s[ks], *(const h8*)&Win3F[(ks * 64 + l) * 8], acc, 0, 0, 0);
        if (li < 4) {
            const float bc = b_in3[li];
#pragma unroll
            for (int r = 0; r < 4; ++r) {
                float a0 = acc[r] + bc;
                float mx = fmaxf(a0, __shfl_xor(a0, 1));
                mx = fmaxf(mx, __shfl_xor(mx, 2));
                float ee = __expf(a0 - mx);
                float sm = ee + __shfl_xor(ee, 1);
                sm += __shfl_xor(sm, 2);
                w3_all[(f0 + (g << 2) + r) * N_ + li] = __fdividef(ee, sm);
            }
        }
    }
    {
        const int ct = (wv == 0) ? 7 : wv - 1;
        h8 v0 = *(const h8*)&afV[afi64(li, 0, g)];
        h8 v1 = *(const h8*)&afV[afi64(li, 1, g)];
        const int col = (ct << 4) + li;
        const float bb = b_ig[col];
        f4 acc = {bb, bb, bb, bb};
        acc = __builtin_amdgcn_mfma_f32_16x16x32_f16(
            v0, *(const h8*)&WigF[((0 * 8 + ct) * 64 + l) * 8], acc, 0, 0, 0);
        acc = __builtin_amdgcn_mfma_f32_16x16x32_f16(
            v1, *(const h8*)&WigF[((1 * 8 + ct) * 64 + l) * 8], acc, 0, 0, 0);
#pragma unroll
        for (int r = 0; r < 4; ++r)
            gIn_all[(f0 + (g << 2) + r) * 2 * S_ + col] = acc[r];
    }
}

// ---------------------------------------------------------------------------
// K2: sequential scan. Mi + loop-invariant B-fragments in REGISTERS.
// amdgpu_waves_per_eu(4,4): pin occupancy target so the allocator uses the
// full 128-VGPR budget instead of spilling at a 64-VGPR/8-wave target
// (LDS=81KB already limits us to 1 workgroup = 4 waves/SIMD).
// ---------------------------------------------------------------------------
__global__ __launch_bounds__(1024)
__attribute__((amdgpu_waves_per_eu(4, 4)))
void k2_scan(const float* __restrict__ v_all, const float* __restrict__ gIn_all,
             const float* __restrict__ w3_all,
             const float* __restrict__ Wmg, const float* __restrict__ b_mg,
             const float* __restrict__ Wqkv, const float* __restrict__ b_qkv,
             const float* __restrict__ ln_g, const float* __restrict__ ln_b,
             const float* __restrict__ Wrel, const float* __restrict__ b_rel,
             const float* __restrict__ Wvb, const float* __restrict__ b_vb,
             const float* __restrict__ Mi0, const float* __restrict__ Mr0,
             const float* __restrict__ p_ib, const float* __restrict__ p_fb,
             const float* __restrict__ p_a1, const float* __restrict__ p_a2,
             float* __restrict__ tvec_all)
{
    const int tid = threadIdx.x;
    const int b = blockIdx.x;
    const int wv = tid >> 6;
    const int ln = tid & 63;
    const int g  = ln >> 4;
    const int li = ln & 15;

    __shared__ __align__(16) _Float16 AsT[S_ * S_];
    __shared__ __align__(16) _Float16 AsX[S_ * S_];
    __shared__ __align__(16) _Float16 Mif16[S_ * S_];
    __shared__ __align__(16) _Float16 P_op[16 * S_];
    __shared__ __align__(16) _Float16 WmgT[2 * S_ * S_];   // init staging only
    __shared__ __align__(16) _Float16 WvbT[S_ * S_];       // init staging only
    __shared__ __align__(16) _Float16 WrelT[S_ * S_];
    __shared__ __align__(16) _Float16 WqkvT[16 * S_];
    __shared__ __align__(16) float vgT[12 * 68];
    __shared__ __align__(16) float gT[12 * 68];
    __shared__ __align__(16) float lbT[12 * 68];
    __shared__ __align__(16) float vvsT[S_ * 4];
    __shared__ __align__(16) float wvm[N_][S_];
    __shared__ __align__(16) float G2s[N_][S_];
    __shared__ __align__(16) float B2s[N_][S_];
    __shared__ __align__(16) float wavepart[16][S_];
    __shared__ float bmgin[128];
    __shared__ float b_mg_s[128];
    __shared__ __align__(16) float b_vb_s[64];
    __shared__ float b_qkv_s[16];
    __shared__ float vt[S_];
    __shared__ __align__(16) float w3s4[4];
    __shared__ __align__(16) float Amat[N_][N_];
    __shared__ __align__(16) float red1[16], red2[16];

    const float ib = p_ib[0], fb = p_fb[0], a1 = p_a1[0], a2v = p_a2[0];

    // thread's fixed MFMA tile coordinates (same mapping in P1 and P5)
    const int rowbase = (wv & 3) << 4;
    const int arow = rowbase + li;
    const int colI = ((wv >> 2) << 4) + li;

    // ---- init: stage weights, tables; Mi/Mrs -> regs ----
    for (int i = tid; i < 2 * S_ * S_; i += 1024) {
        int k = i >> 7, j = i & 127;
        WmgT[sidx(j, k)] = (_Float16)Wmg[i];
    }
    for (int i = tid; i < S_ * S_; i += 1024) {
        int r = i >> 6, j = i & 63;
        WvbT[sidx(j, r)] = (_Float16)Wvb[i];
    }
    for (int i = tid; i < S_ * S_; i += 1024) {
        int s = i >> 6, r = i & 63;
        WrelT[sidx(r, s)] = (_Float16)Wrel[i];
    }
    if (tid < 16 * S_) {
        int c = tid >> 6, k = tid & 63;
        float w = (c < 12) ? Wqkv[k * 12 + c] : 0.f;
        WqkvT[sidx(c, k)] = (_Float16)w;
    }
    if (tid < 768) {
        int s = tid / 12, c = tid - s * 12;
        gT[c * 68 + s]  = ln_g[tid];
        lbT[c * 68 + s] = ln_b[tid];
    }
    if (tid < 128) b_mg_s[tid] = b_mg[tid];
    else if (tid < 192) b_vb_s[tid - 128] = b_vb[tid - 128];
    else if (tid < 208) b_qkv_s[tid - 192] = (tid - 192 < 12) ? b_qkv[tid - 192] : 0.f;
    if (tid < 1024) P_op[tid] = (_Float16)0.f;
    if (tid < 256) {
        const int m = tid >> 6, r = tid & 63;
        float g2 = 0.f, b2 = 0.f;
        for (int s = 0; s < S_; ++s) {
            float w = Wrel[s * R_ + r];
            g2 = fmaf(ln_g[s * 12 + 8 + m], w, g2);
            b2 = fmaf(ln_b[s * 12 + 8 + m], w, b2);
        }
        G2s[m][r] = g2;
        B2s[m][r] = a1 * b2;
    }
    {   // AsT = tanh(Mi0)
        const int row = tid >> 4, k0 = (tid & 15) << 2;
        const float* mp = Mi0 + (tid << 2);
        h4 t4;
        t4[0] = (_Float16)ftanh(mp[0]); t4[1] = (_Float16)ftanh(mp[1]);
        t4[2] = (_Float16)ftanh(mp[2]); t4[3] = (_Float16)ftanh(mp[3]);
        *(h4*)&AsT[sidx(row, k0)] = t4;
    }
    // Mi -> registers (rows rowbase+(g<<2)+r, col colI)
    f4 mi_reg;
#pragma unroll
    for (int r = 0; r < 4; ++r)
        mi_reg[r] = Mi0[(rowbase + (g << 2) + r) * 64 + colI];
    // Mrs -> registers
    f4 mrs0, mrs1, mrs2, mrs3, a1brel4;
    {
        const int s0i = tid >> 4, r4i = (tid & 15) << 2;
        const float* mrp = Mr0 + s0i * 64 + r4i;
        mrs0 = *(const f4*)&mrp[0];
        mrs1 = *(const f4*)&mrp[4096];
        mrs2 = *(const f4*)&mrp[8192];
        mrs3 = *(const f4*)&mrp[12288];
        f4 br = *(const f4*)&b_rel[r4i];
        a1brel4 = a1 * br;
    }
    if (tid < 64) vt[tid] = v_all[b * S_ + tid];
    else if (tid < 68) w3s4[tid - 64] = w3_all[b * N_ + (tid - 64)];
    if (tid >= 128 && tid < 256)
        bmgin[tid - 128] = b_mg[tid - 128] + gIn_all[b * 2 * S_ + (tid - 128)];
    __syncthreads();

    // loop-invariant B-fragments -> registers
    const h8 wmgI0 = *(const h8*)&WmgT[fidx(colI, 0, g)];
    const h8 wmgI1 = *(const h8*)&WmgT[fidx(colI, 1, g)];
    const h8 wmgF0 = *(const h8*)&WmgT[fidx(colI + 64, 0, g)];
    const h8 wmgF1 = *(const h8*)&WmgT[fidx(colI + 64, 1, g)];
    const h8 wvb0  = *(const h8*)&WvbT[fidx(colI, 0, g)];
    const h8 wvb1  = *(const h8*)&WvbT[fidx(colI, 1, g)];

    for (int t = 0; t < T_; ++t) {
        const int f = t * B_ + b;

        // ===== P1: gates MFMA (16 waves); prefetch t+1 inputs =============
        float pf = 0.f;
        {
            const int fn = ((t + 1 < T_) ? t + 1 : t) * B_ + b;
            if (tid >= 512 && tid < 576) pf = v_all[fn * S_ + (tid - 512)];
            else if (tid >= 576 && tid < 580) pf = w3_all[fn * N_ + (tid - 576)];
            else if (tid >= 640 && tid < 768) pf = gIn_all[fn * 2 * S_ + (tid - 640)];
        }
        {
            h8 af0 = *(const h8*)&AsT[fidx(arow, 0, g)];
            h8 af1 = *(const h8*)&AsT[fidx(arow, 1, g)];
            const float bi = bmgin[colI], bfv = bmgin[colI + 64];
            f4 accI = {bi, bi, bi, bi};
            f4 accF = {bfv, bfv, bfv, bfv};
            accI = __builtin_amdgcn_mfma_f32_16x16x32_f16(af0, wmgI0, accI, 0, 0, 0);
            accI = __builtin_amdgcn_mfma_f32_16x16x32_f16(af1, wmgI1, accI, 0, 0, 0);
            accF = __builtin_amdgcn_mfma_f32_16x16x32_f16(af0, wmgF0, accF, 0, 0, 0);
            accF = __builtin_amdgcn_mfma_f32_16x16x32_f16(af1, wmgF1, accF, 0, 0, 0);
            const float vc = vt[colI];
#pragma unroll
            for (int r = 0; r < 4; ++r) {
                const int row = rowbase + (g << 2) + r;
                const float gi = fsigm(accI[r] + ib);
                const float gf = fsigm(accF[r] + fb);
                const float mn = gf * mi_reg[r] + gi * ftanh(vt[row] * vc);
                mi_reg[r] = mn;
                Mif16[sidx(row, colI)] = (_Float16)mn;
            }
        }
        __syncthreads();   // (1)

        // ===== P2: qkv MFMA (w0-3) + LN 16-partials + vgT/P_op ============
        if (wv < 4) {
            const int rb2 = wv << 4;
            h8 af0 = *(const h8*)&Mif16[fidx(rb2 + li, 0, g)];
            h8 af1 = *(const h8*)&Mif16[fidx(rb2 + li, 1, g)];
            const float bq = b_qkv_s[li];
            f4 qacc = {bq, bq, bq, bq};
            qacc = __builtin_amdgcn_mfma_f32_16x16x32_f16(af0, *(const h8*)&WqkvT[fidx(li, 0, g)], qacc, 0, 0, 0);
            qacc = __builtin_amdgcn_mfma_f32_16x16x32_f16(af1, *(const h8*)&WqkvT[fidx(li, 1, g)], qacc, 0, 0, 0);
            float s1 = 0.f, s2 = 0.f;
            if (li < 12) {
                const int srow = rb2 + (g << 2);
                f4 g4 = *(const f4*)&gT[li * 68 + srow];
                f4 vg = qacc * g4;
                *(f4*)&vgT[li * 68 + srow] = vg;
                s1 = (qacc[0] + qacc[1]) + (qacc[2] + qacc[3]);
                f4 sq = qacc * qacc;
                s2 = (sq[0] + sq[1]) + (sq[2] + sq[3]);
                if (li >= 8) {
                    h4 p4 = __builtin_convertvector(vg, h4);
                    *(h4*)&P_op[sidx(li - 8, srow)] = p4;
                }
            }
#pragma unroll
            for (int off = 8; off; off >>= 1) {
                s1 += __shfl_down(s1, off); s2 += __shfl_down(s2, off);
            }
            if (li == 0) { red1[(wv << 2) + g] = s1; red2[(wv << 2) + g] = s2; }
        }
        __syncthreads();   // (2)

        // ===== P3: wvm MFMA (w0-3); A-scores (w4-7); vvsT (w8-11) =========
        if (wv < 12) {
            f4 rA = *(const f4*)&red1[0];
            rA += *(const f4*)&red1[4];
            rA += *(const f4*)&red1[8];
            rA += *(const f4*)&red1[12];
            f4 rB = *(const f4*)&red2[0];
            rB += *(const f4*)&red2[4];
            rB += *(const f4*)&red2[8];
            rB += *(const f4*)&red2[12];
            const float sA = (rA[0] + rA[1]) + (rA[2] + rA[3]);
            const float sB = (rB[0] + rB[1]) + (rB[2] + rB[3]);
            const float mu = sA * (1.f / 768.f);
            const float var = sB * (1.f / 768.f) - mu * mu;
            const float rstd = rsqrtf(var + 1e-5f);
            const float murstd = mu * rstd;
            if (wv < 4) {
                h8 af0 = *(const h8*)&P_op[fidx(li, 0, g)];
                h8 af1 = *(const h8*)&P_op[fidx(li, 1, g)];
                const int col = (wv << 4) + li;
                f4 acc = {0.f, 0.f, 0.f, 0.f};
                acc = __builtin_amdgcn_mfma_f32_16x16x32_f16(af0, *(const h8*)&WrelT[fidx(col, 0, g)], acc, 0, 0, 0);
                acc = __builtin_amdgcn_mfma_f32_16x16x32_f16(af1, *(const h8*)&WrelT[fidx(col, 1, g)], acc, 0, 0, 0);
                if (ln < 16) {
                    const float sa = a1 * rstd;
                    const float sb = -a1 * murstd;
#pragma unroll
                    for (int r = 0; r < 4; ++r)
                        wvm[r][col] = sa * acc[r] + sb * G2s[r][col] + B2s[r][col];
                }
            } else if (wv < 8) {
                const int n = wv - 4;
                const int s0 = li << 2;
                f4 vgq = *(const f4*)&vgT[n * 68 + s0];
                f4 gq  = *(const f4*)&gT [n * 68 + s0];
                f4 lbq = *(const f4*)&lbT[n * 68 + s0];
                f4 qv  = rstd * vgq - murstd * gq + lbq;
                const int kr = 4 + g;
                f4 vgk = *(const f4*)&vgT[kr * 68 + s0];
                f4 gk  = *(const f4*)&gT [kr * 68 + s0];
                f4 lbk = *(const f4*)&lbT[kr * 68 + s0];
                f4 kv  = rstd * vgk - murstd * gk + lbk;
                f4 pr = qv * kv;
                float a = (pr[0] + pr[1]) + (pr[2] + pr[3]);
                a += __shfl_down(a, 8);
                a += __shfl_down(a, 4);
                a += __shfl_down(a, 2);
                a += __shfl_down(a, 1);
                a *= 0.125f;
                float s0v = __shfl(a, 0), s1v = __shfl(a, 16);
                float s2v = __shfl(a, 32), s3v = __shfl(a, 48);
                if (li == 0) {
                    float mx = fmaxf(fmaxf(s0v, s1v), fmaxf(s2v, s3v));
                    float e0 = __expf(s0v - mx), e1 = __expf(s1v - mx);
                    float e2 = __expf(s2v - mx), e3 = __expf(s3v - mx);
                    float inv = __fdividef(1.f, e0 + e1 + e2 + e3);
                    float ev = (g == 0) ? e0 : (g == 1) ? e1 : (g == 2) ? e2 : e3;
                    Amat[n][g] = ev * inv;
                }
            } else {
                const int m = wv - 8;
                const int c = (8 + m) * 68 + ln;
                vvsT[(ln << 2) + m] = rstd * vgT[c] - murstd * gT[c] + lbT[c];
            }
        }
        __syncthreads();   // (3)

        // ===== P4: in-register Mrs update (packed) + transfer + tvec ======
        {
            const int s = tid >> 4, rq = tid & 15, r4 = rq << 2;
            f4 Am0 = *(const f4*)&Amat[0][0];
            f4 Am1 = *(const f4*)&Amat[1][0];
            f4 Am2 = *(const f4*)&Amat[2][0];
            f4 Am3 = *(const f4*)&Amat[3][0];
            f4 w3r = *(const f4*)&w3s4[0];
            f4 vv4 = *(const f4*)&vvsT[s << 2];
            f4 wvA4 = *(const f4*)&wvm[0][r4];
            f4 wvB4 = *(const f4*)&wvm[1][r4];
            f4 wvC4 = *(const f4*)&wvm[2][r4];
            f4 wvD4 = *(const f4*)&wvm[3][r4];
            {
                const float c0 = Am0[0] * vv4[0], c1 = Am0[1] * vv4[1];
                const float c2 = Am0[2] * vv4[2], c3 = Am0[3] * vv4[3];
                mrs0 += a1brel4 + c0 * wvA4 + c1 * wvB4 + c2 * wvC4 + c3 * wvD4;
            }
            {
                const float c0 = Am1[0] * vv4[0], c1 = Am1[1] * vv4[1];
                const float c2 = Am1[2] * vv4[2], c3 = Am1[3] * vv4[3];
                mrs1 += a1brel4 + c0 * wvA4 + c1 * wvB4 + c2 * wvC4 + c3 * wvD4;
            }
            {
                const float c0 = Am2[0] * vv4[0], c1 = Am2[1] * vv4[1];
                const float c2 = Am2[2] * vv4[2], c3 = Am2[3] * vv4[3];
                mrs2 += a1brel4 + c0 * wvA4 + c1 * wvB4 + c2 * wvC4 + c3 * wvD4;
            }
            {
                const float c0 = Am3[0] * vv4[0], c1 = Am3[1] * vv4[1];
                const float c2 = Am3[2] * vv4[2], c3 = Am3[3] * vv4[3];
                mrs3 += a1brel4 + c0 * wvA4 + c1 * wvB4 + c2 * wvC4 + c3 * wvD4;
            }
            f4 trv = w3r[0] * mrs0 + w3r[1] * mrs1 + w3r[2] * mrs2 + w3r[3] * mrs3;
            h4 trh = __builtin_convertvector(trv, h4);
            *(h4*)&AsX[sidx(s, r4)] = trh;
            f4 tp = vt[s] * trv;
            {
                f4 o;
                o[0] = __shfl_xor(tp[0], 16); o[1] = __shfl_xor(tp[1], 16);
                o[2] = __shfl_xor(tp[2], 16); o[3] = __shfl_xor(tp[3], 16);
                tp += o;
                o[0] = __shfl_xor(tp[0], 32); o[1] = __shfl_xor(tp[1], 32);
                o[2] = __shfl_xor(tp[2], 32); o[3] = __shfl_xor(tp[3], 32);
                tp += o;
            }
            if (ln < 16) *(f4*)&wavepart[wv][r4] = tp;
        }
        __syncthreads();   // (4)

        // ===== P5: Wvb MFMA (16 waves) + Mi/AsT; tvec (w15); stage ========
        {
            h8 af0 = *(const h8*)&AsX[fidx(arow, 0, g)];
            h8 af1 = *(const h8*)&AsX[fidx(arow, 1, g)];
            const float bv = b_vb_s[colI];
            f4 acc = {bv, bv, bv, bv};
            acc = __builtin_amdgcn_mfma_f32_16x16x32_f16(af0, wvb0, acc, 0, 0, 0);
            acc = __builtin_amdgcn_mfma_f32_16x16x32_f16(af1, wvb1, acc, 0, 0, 0);
#pragma unroll
            for (int r = 0; r < 4; ++r) {
                const int row = rowbase + (g << 2) + r;
                const float mn = mi_reg[r] + a2v * ftanh(acc[r]);
                mi_reg[r] = mn;
                AsT[sidx(row, colI)] = (_Float16)ftanh(mn);
            }
        }
        if (wv == 15) {
            float tv = 0.f;
#pragma unroll
            for (int w = 0; w < 16; ++w) tv += wavepart[w][ln];
            tvec_all[f * S_ + ln] = tv;
        } else if (tid >= 512 && tid < 768) {
            if (tid < 576) vt[tid - 512] = pf;
            else if (tid < 580) w3s4[tid - 576] = pf;
            else if (tid >= 640) bmgin[tid - 640] = b_mg_s[tid - 640] + pf;
        }
        __syncthreads();   // (5)
    }
}

// ---------------------------------------------------------------------------
// K3: MFMA post-pass — unchanged
// ---------------------------------------------------------------------------
__global__ __launch_bounds__(512)
void k3_post(const float* __restrict__ tvec_all, const float* __restrict__ xo_all,
             const _Float16* __restrict__ hW,
             const float* __restrict__ b_rel3, const float* __restrict__ b_m1,
             const float* __restrict__ b_m2, const float* __restrict__ b_out,
             const float* __restrict__ fc_g, const float* __restrict__ fc_b,
             const float* __restrict__ b_fc, float* __restrict__ out)
{
    __shared__ __align__(16) _Float16 afA[16 * 512];
    __shared__ __align__(16) _Float16 afB[16 * 512];
    __shared__ __align__(16) _Float16 afT[16 * 64];
    __shared__ __align__(16) _Float16 afO[16 * 64];
    __shared__ __align__(16) float ybuf[16 * 512];
    __shared__ float mus[16], rsts[16];
    const int tid = threadIdx.x;
    const int wv = tid >> 6, l = tid & 63, li = l & 15, g = l >> 4;
    const int f0 = blockIdx.x * 16;

    const _Float16* Wrel3F = hW + OFF_WREL3;
    const _Float16* Wm1F   = hW + OFF_WM1;
    const _Float16* Wm2F   = hW + OFF_WM2;
    const _Float16* WoutF  = hW + OFF_WOUT;
    const _Float16* WfcF   = hW + OFF_WFC;

    for (int i = tid; i < 16 * 64; i += 512) {
        int row = i >> 6, k = i & 63;
        afT[afw64(row, k)] = (_Float16)tvec_all[(f0 + row) * O_ + k];
    }
    __syncthreads();

    if (wv < 4) {
        h8 t0 = *(const h8*)&afT[afi64(li, 0, g)];
        h8 t1 = *(const h8*)&afT[afi64(li, 1, g)];
        const int col = (wv << 4) + li;
        const float bb = b_rel3[col];
        f4 acc = {bb, bb, bb, bb};
        acc = __builtin_amdgcn_mfma_f32_16x16x32_f16(
            t0, *(const h8*)&Wrel3F[((0 * 4 + wv) * 64 + l) * 8], acc, 0, 0, 0);
        acc = __builtin_amdgcn_mfma_f32_16x16x32_f16(
            t1, *(const h8*)&Wrel3F[((1 * 4 + wv) * 64 + l) * 8], acc, 0, 0, 0);
#pragma unroll
        for (int r = 0; r < 4; ++r) {
            const int row = (g << 2) + r;
            const float o = acc[r] + xo_all[(f0 + row) * O_ + col];
            afO[afw64(row, col)] = (_Float16)o;
        }
    }
    __syncthreads();

    {
        h8 o0 = *(const h8*)&afO[afi64(li, 0, g)];
        h8 o1 = *(const h8*)&afO[afi64(li, 1, g)];
#pragma unroll
        for (int c4 = 0; c4 < 4; ++c4) {
            const int ct = (wv << 2) + c4;
            const int col = (ct << 4) + li;
            const float bb = b_m1[col];
            f4 acc = {bb, bb, bb, bb};
            acc = __builtin_amdgcn_mfma_f32_16x16x32_f16(
                o0, *(const h8*)&Wm1F[((0 * 32 + ct) * 64 + l) * 8], acc, 0, 0, 0);
            acc = __builtin_amdgcn_mfma_f32_16x16x32_f16(
                o1, *(const h8*)&Wm1F[((1 * 32 + ct) * 64 + l) * 8], acc, 0, 0, 0);
#pragma unroll
            for (int r = 0; r < 4; ++r)
                afA[afw512((g << 2) + r, col)] = (_Float16)fmaxf(acc[r], 0.f);
        }
    }
    __syncthreads();

    {
        h8 a[16];
#pragma unroll
        for (int ks = 0; ks < 16; ++ks) a[ks] = *(const h8*)&afA[afi512(li, ks, g)];
#pragma unroll
        for (int c4 = 0; c4 < 4; ++c4) {
            const int ct = (wv << 2) + c4;
            const int col = (ct << 4) + li;
            const float bb = b_m2[col];
            f4 acc = {bb, bb, bb, bb};
#pragma unroll
            for (int ks = 0; ks < 16; ++ks)
                acc = __builtin_amdgcn_mfma_f32_16x16x32_f16(
                    a[ks], *(const h8*)&Wm2F[((ks * 32 + ct) * 64 + l) * 8], acc, 0, 0, 0);
#pragma unroll
            for (int r = 0; r < 4; ++r)
                afB[afw512((g << 2) + r, col)] = (_Float16)fmaxf(acc[r], 0.f);
        }
    }
    __syncthreads();

    {
        h8 a[16];
#pragma unroll
        for (int ks = 0; ks < 16; ++ks) a[ks] = *(const h8*)&afB[afi512(li, ks, g)];
#pragma unroll
        for (int c4 = 0; c4 < 4; ++c4) {
            const int ct = (wv << 2) + c4;
            const int col = (ct << 4) + li;
            const float bb = b_out[col];
            f4 acc = {bb, bb, bb, bb};
#pragma unroll
            for (int ks = 0; ks < 16; ++ks)
                acc = __builtin_amdgcn_mfma_f32_16x16x32_f16(
                    a[ks], *(const h8*)&WoutF[((ks * 32 + ct) * 64 + l) * 8], acc, 0, 0, 0);
#pragma unroll
            for (int r = 0; r < 4; ++r)
                ybuf[((g << 2) + r) * 512 + col] = acc[r];
        }
    }
    __syncthreads();

    {
        const int r = tid >> 5, l32 = tid & 31;
        float s1 = 0.f, s2 = 0.f;
        for (int k = l32; k < 512; k += 32) {
            float y = ybuf[r * 512 + k];
            s1 += y; s2 += y * y;
        }
#pragma unroll
        for (int off = 16; off; off >>= 1) {
            s1 += __shfl_down(s1, off, 32);
            s2 += __shfl_down(s2, off, 32);
        }
        if (l32 == 0) {
            float mu = s1 * (1.f / 512.f);
            float var = s2 * (1.f / 512.f) - mu * mu;
            mus[r] = mu; rsts[r] = rsqrtf(var + 1e-5f);
        }
    }
    __syncthreads();
    for (int i = tid; i < 16 * 512; i += 512) {
        int row = i >> 9, col = i & 511;
        float yn = (ybuf[row * 512 + col] - mus[row]) * rsts[row] * fc_g[col] + fc_b[col];
        afA[afw512(row, col)] = (_Float16)fmaxf(yn, 0.f);
    }
    __syncthreads();

    {
        h8 a[16];
#pragma unroll
        for (int ks = 0; ks < 16; ++ks) a[ks] = *(const h8*)&afA[afi512(li, ks, g)];
        const int col = (wv << 4) + li;
        const float bb = b_fc[col];
        f4 acc = {bb, bb, bb, bb};
#pragma unroll
        for (int ks = 0; ks < 16; ++ks)
            acc = __builtin_amdgcn_mfma_f32_16x16x32_f16(
                a[ks], *(const h8*)&WfcF[((ks * 8 + wv) * 64 + l) * 8], acc, 0, 0, 0);
#pragma unroll
        for (int r = 0; r < 4; ++r) {
            const int row = (g << 2) + r;
            const int f = f0 + row, t = f >> 5, bo = f & 31;
            out[bo * (V_ * T_) + col * T_ + t] = acc[r];
        }
    }
}

// ---------------------------------------------------------------------------
extern "C" void kernel_launch(void* const* d_in, const int* in_sizes, int n_in,
                              void* d_out, int out_size, void* d_ws, size_t ws_size,
                              hipStream_t stream)
{
    (void)in_sizes; (void)n_in; (void)out_size; (void)ws_size;
    const int*   ids   = (const int*)  d_in[0];
    const float* emb   = (const float*)d_in[1];
    const float* We    = (const float*)d_in[2];
    const float* be    = (const float*)d_in[3];
    const float* Win   = (const float*)d_in[4];
    const float* b_in  = (const float*)d_in[5];
    const float* Win2  = (const float*)d_in[6];
    const float* b_in2 = (const float*)d_in[7];
    const float* Win3  = (const float*)d_in[8];
    const float* b_in3 = (const float*)d_in[9];
    const float* Wig   = (const float*)d_in[10];
    const float* b_ig  = (const float*)d_in[11];
    const float* Wmg   = (const float*)d_in[12];
    const float* b_mg  = (const float*)d_in[13];
    const float* ibp   = (const float*)d_in[14];
    const float* fbp   = (const float*)d_in[15];
    const float* Wqkv  = (const float*)d_in[16];
    const float* b_qkv = (const float*)d_in[17];
    const float* ln_g  = (const float*)d_in[18];
    const float* ln_b  = (const float*)d_in[19];
    const float* a1p   = (const float*)d_in[20];
    const float* a2p   = (const float*)d_in[21];
    const float* Wrel  = (const float*)d_in[22];
    const float* b_rel = (const float*)d_in[23];
    const float* Wvb   = (const float*)d_in[24];
    const float* b_vb  = (const float*)d_in[25];
    const float* Wrel3 = (const float*)d_in[26];
    const float* b_rel3= (const float*)d_in[27];
    const float* Wm1   = (const float*)d_in[28];
    const float* b_m1  = (const float*)d_in[29];
    const float* Wm2   = (const float*)d_in[30];
    const float* b_m2  = (const float*)d_in[31];
    const float* Wout  = (const float*)d_in[32];
    const float* b_out = (const float*)d_in[33];
    const float* Mi0   = (const float*)d_in[34];
    const float* Mr0   = (const float*)d_in[35];
    const float* fc_g  = (const float*)d_in[36];
    const float* fc_b  = (const float*)d_in[37];
    const float* Wfc   = (const float*)d_in[38];
    const float* b_fc  = (const float*)d_in[39];

    float* ws = (float*)d_ws;
    float* v_all    = ws;
    float* gIn_all  = v_all    + T_ * B_ * S_;
    float* w3_all   = gIn_all  + T_ * B_ * 2 * S_;
    float* xo_all   = w3_all   + T_ * B_ * N_;
    float* tvec_all = xo_all   + T_ * B_ * O_;
    _Float16* hW    = (_Float16*)(tvec_all + T_ * B_ * O_);

    k0_conv<<<dim3((HW_TOTAL + 255) / 256), dim3(256), 0, stream>>>(
        We, Win, Win2, Win3, Wig, Wrel3, Wm1, Wm2, Wout, Wfc, hW);

    k1_pre<<<dim3((T_ * B_) / 16), dim3(512), 0, stream>>>(
        ids, emb, hW, be, b_in, b_in2, b_in3, b_ig,
        v_all, gIn_all, w3_all, xo_all);

    k2_scan<<<dim3(B_), dim3(1024), 0, stream>>>(
        v_all, gIn_all, w3_all,
        Wmg, b_mg, Wqkv, b_qkv, ln_g, ln_b,
        Wrel, b_rel, Wvb, b_vb,
        Mi0, Mr0, ibp, fbp, a1p, a2p, tvec_all);

    k3_post<<<dim3((T_ * B_) / 16), dim3(512), 0, stream>>>(
        tvec_all, xo_all, hW, b_rel3, b_m1, b_m2, b_out, fc_g, fc_b, b_fc,
        (float*)d_out);
}

// Round 11
// 694.833 us; speedup vs baseline: 1.1667x; 1.1667x over previous
//
#include <hip/hip_runtime.h>
#include <hip/hip_fp16.h>
#include <math.h>

#define T_ 128
#define B_ 32
#define D_ 512
#define V_ 128
#define S_ 64
#define N_ 4
#define R_ 64
#define O_ 64

typedef _Float16 h4 __attribute__((ext_vector_type(4)));
typedef _Float16 h8 __attribute__((ext_vector_type(8)));
typedef float f4 __attribute__((ext_vector_type(4)));

__device__ __forceinline__ float fsigm(float x) {
    return __fdividef(1.0f, 1.0f + __expf(-x));
}
__device__ __forceinline__ float ftanh(float x) {
    float e = __expf(2.f * x);
    return 1.f - __fdividef(2.f, e + 1.f);
}

// ---- h8-contiguous fragment layout for [rows][64] f16 operand tiles (k2) ----
__device__ __forceinline__ int fidx(int row, int ks, int g) {
    return row * 64 + ((((ks << 2) | g) ^ (row & 7)) << 3);
}
__device__ __forceinline__ int sidx(int row, int k) {
    int ks = k >> 5, u = (k >> 4) & 1, gg = (k >> 2) & 3, e = k & 3;
    return row * 64 + ((((ks << 2) | gg) ^ (row & 7)) << 3) + (u << 2) + e;
}

// ---- A-fragment LDS layouts for K=512 / K=64 (k1/k3) ----
__device__ __forceinline__ int afi512(int row, int ks, int g) {
    return row * 512 + ((((ks << 2) | g) ^ (row & 7)) << 3);
}
__device__ __forceinline__ int afw512(int row, int k) {
    return row * 512 + (((((k >> 5) << 2) | ((k >> 2) & 3)) ^ (row & 7)) << 3)
         + (((k >> 4) & 1) << 2) + (k & 3);
}
__device__ __forceinline__ int afi64(int row, int ks, int g) {
    return row * 64 + ((((ks << 2) | g) ^ (row & 7)) << 3);
}
__device__ __forceinline__ int afw64(int row, int k) {
    return row * 64 + (((((k >> 5) << 2) | ((k >> 2) & 3)) ^ (row & 7)) << 3)
         + (((k >> 4) & 1) << 2) + (k & 3);
}

// fragment-layout weight segment offsets (halves) within hW
#define OFF_WE    0
#define OFF_WIN   262144
#define OFF_WIN2  294912
#define OFF_WIN3  327680
#define OFF_WIG   335872
#define OFF_WREL3 344064
#define OFF_WM1   348160
#define OFF_WM2   380928
#define OFF_WOUT  643072
#define OFF_WFC   905216
#define HW_TOTAL  970752

// ---------------------------------------------------------------------------
// K0: convert 10 weight matrices to fragment-interleaved fp16 — unchanged
// ---------------------------------------------------------------------------
__global__ __launch_bounds__(256)
void k0_conv(const float* __restrict__ We, const float* __restrict__ Win,
             const float* __restrict__ Win2, const float* __restrict__ Win3,
             const float* __restrict__ Wig, const float* __restrict__ Wrel3,
             const float* __restrict__ Wm1, const float* __restrict__ Wm2,
             const float* __restrict__ Wout, const float* __restrict__ Wfc,
             _Float16* __restrict__ outh)
{
    int idx = blockIdx.x * 256 + threadIdx.x;
    if (idx >= HW_TOTAL) return;
    const float* W; int base, Nn, NT;
    if (idx < OFF_WIN)        { W = We;    base = OFF_WE;    Nn = 512; NT = 32; }
    else if (idx < OFF_WIN2)  { W = Win;   base = OFF_WIN;   Nn = 64;  NT = 4;  }
    else if (idx < OFF_WIN3)  { W = Win2;  base = OFF_WIN2;  Nn = 64;  NT = 4;  }
    else if (idx < OFF_WIG)   { W = Win3;  base = OFF_WIN3;  Nn = 4;   NT = 1;  }
    else if (idx < OFF_WREL3) { W = Wig;   base = OFF_WIG;   Nn = 128; NT = 8;  }
    else if (idx < OFF_WM1)   { W = Wrel3; base = OFF_WREL3; Nn = 64;  NT = 4;  }
    else if (idx < OFF_WM2)   { W = Wm1;   base = OFF_WM1;   Nn = 512; NT = 32; }
    else if (idx < OFF_WOUT)  { W = Wm2;   base = OFF_WM2;   Nn = 512; NT = 32; }
    else if (idx < OFF_WFC)   { W = Wout;  base = OFF_WOUT;  Nn = 512; NT = 32; }
    else                      { W = Wfc;   base = OFF_WFC;   Nn = 128; NT = 8;  }
    int local = idx - base;
    int e = local & 7, fr = local >> 3;
    int l = fr & 63, ctks = fr >> 6;
    int ks = ctks / NT, ct = ctks - ks * NT;
    int col = ct * 16 + (l & 15);
    int k = ks * 32 + ((e >> 2) << 4) + ((l >> 4) << 2) + (e & 3);
    outh[idx] = (col < Nn) ? (_Float16)W[k * Nn + col] : (_Float16)0.f;
}

// ---------------------------------------------------------------------------
// K1: MFMA precompute — unchanged
// ---------------------------------------------------------------------------
__global__ __launch_bounds__(512)
void k1_pre(const int* __restrict__ ids, const float* __restrict__ emb,
            const _Float16* __restrict__ hW,
            const float* __restrict__ be, const float* __restrict__ b_in,
            const float* __restrict__ b_in2, const float* __restrict__ b_in3,
            const float* __restrict__ b_ig,
            float* __restrict__ v_all, float* __restrict__ gIn_all,
            float* __restrict__ w3_all, float* __restrict__ xo_all)
{
    __shared__ __align__(16) _Float16 afE[16 * 512];
    __shared__ __align__(16) _Float16 afS[16 * 512];
    __shared__ __align__(16) _Float16 afV[16 * 64];
    const int tid = threadIdx.x;
    const int wv = tid >> 6, l = tid & 63, li = l & 15, g = l >> 4;
    const int f0 = blockIdx.x * 16;

    const _Float16* WeF   = hW + OFF_WE;
    const _Float16* WinF  = hW + OFF_WIN;
    const _Float16* Win2F = hW + OFF_WIN2;
    const _Float16* Win3F = hW + OFF_WIN3;
    const _Float16* WigF  = hW + OFF_WIG;

#pragma unroll
    for (int row = 0; row < 16; ++row) {
        const int f = f0 + row, t = f >> 5, bb = f & 31;
        const int id = ids[bb * T_ + t];
        afE[afw512(row, tid)] = (_Float16)emb[id * D_ + tid];
    }
    __syncthreads();

    {
        h8 a[16];
#pragma unroll
        for (int ks = 0; ks < 16; ++ks) a[ks] = *(const h8*)&afE[afi512(li, ks, g)];
#pragma unroll
        for (int c4 = 0; c4 < 4; ++c4) {
            const int ct = (wv << 2) + c4;
            const int col = (ct << 4) + li;
            const float bb = be[col];
            f4 acc = {bb, bb, bb, bb};
#pragma unroll
            for (int ks = 0; ks < 16; ++ks)
                acc = __builtin_amdgcn_mfma_f32_16x16x32_f16(
                    a[ks], *(const h8*)&WeF[((ks * 32 + ct) * 64 + l) * 8], acc, 0, 0, 0);
#pragma unroll
            for (int r = 0; r < 4; ++r)
                afS[afw512((g << 2) + r, col)] = (_Float16)acc[r];
        }
    }
    __syncthreads();

    h8 s[16];
#pragma unroll
    for (int ks = 0; ks < 16; ++ks) s[ks] = *(const h8*)&afS[afi512(li, ks, g)];
    if (wv < 4) {
        const int col = (wv << 4) + li;
        const float bb = b_in[col];
        f4 acc = {bb, bb, bb, bb};
#pragma unroll
        for (int ks = 0; ks < 16; ++ks)
            acc = __builtin_amdgcn_mfma_f32_16x16x32_f16(
                s[ks], *(const h8*)&WinF[((ks * 4 + wv) * 64 + l) * 8], acc, 0, 0, 0);
#pragma unroll
        for (int r = 0; r < 4; ++r) {
            const int row = (g << 2) + r;
            v_all[(f0 + row) * S_ + col] = acc[r];
            afV[afw64(row, col)] = (_Float16)acc[r];
        }
    } else {
        const int ct = wv - 4;
        const int col = (ct << 4) + li;
        const float bb = b_in2[col];
        f4 acc = {bb, bb, bb, bb};
#pragma unroll
        for (int ks = 0; ks < 16; ++ks)
            acc = __builtin_amdgcn_mfma_f32_16x16x32_f16(
                s[ks], *(const h8*)&Win2F[((ks * 4 + ct) * 64 + l) * 8], acc, 0, 0, 0);
#pragma unroll
        for (int r = 0; r < 4; ++r)
            xo_all[(f0 + (g << 2) + r) * O_ + col] = acc[r];
    }
    __syncthreads();

    if (wv == 0) {
        f4 acc = {0.f, 0.f, 0.f, 0.f};
#pragma unroll
        for (int ks = 0; ks < 16; ++ks)
            acc = __builtin_amdgcn_mfma_f32_16x16x32_f16(
                s[ks], *(const h8*)&Win3F[(ks * 64 + l) * 8], acc, 0, 0, 0);
        if (li < 4) {
            const float bc = b_in3[li];
#pragma unroll
            for (int r = 0; r < 4; ++r) {
                float a0 = acc[r] + bc;
                float mx = fmaxf(a0, __shfl_xor(a0, 1));
                mx = fmaxf(mx, __shfl_xor(mx, 2));
                float ee = __expf(a0 - mx);
                float sm = ee + __shfl_xor(ee, 1);
                sm += __shfl_xor(sm, 2);
                w3_all[(f0 + (g << 2) + r) * N_ + li] = __fdividef(ee, sm);
            }
        }
    }
    {
        const int ct = (wv == 0) ? 7 : wv - 1;
        h8 v0 = *(const h8*)&afV[afi64(li, 0, g)];
        h8 v1 = *(const h8*)&afV[afi64(li, 1, g)];
        const int col = (ct << 4) + li;
        const float bb = b_ig[col];
        f4 acc = {bb, bb, bb, bb};
        acc = __builtin_amdgcn_mfma_f32_16x16x32_f16(
            v0, *(const h8*)&WigF[((0 * 8 + ct) * 64 + l) * 8], acc, 0, 0, 0);
        acc = __builtin_amdgcn_mfma_f32_16x16x32_f16(
            v1, *(const h8*)&WigF[((1 * 8 + ct) * 64 + l) * 8], acc, 0, 0, 0);
#pragma unroll
        for (int r = 0; r < 4; ++r)
            gIn_all[(f0 + (g << 2) + r) * 2 * S_ + col] = acc[r];
    }
}

// ---------------------------------------------------------------------------
// K2: sequential scan — REVERTED to the round-8 version (best measured:
// 660 us, no spill). Mi + weight B-operands live in LDS; the 64-VGPR cap
// on 1024-thread blocks makes register-hoisting spill (rounds 9-10).
// ---------------------------------------------------------------------------
__global__ __launch_bounds__(1024, 4)
void k2_scan(const float* __restrict__ v_all, const float* __restrict__ gIn_all,
             const float* __restrict__ w3_all,
             const float* __restrict__ Wmg, const float* __restrict__ b_mg,
             const float* __restrict__ Wqkv, const float* __restrict__ b_qkv,
             const float* __restrict__ ln_g, const float* __restrict__ ln_b,
             const float* __restrict__ Wrel, const float* __restrict__ b_rel,
             const float* __restrict__ Wvb, const float* __restrict__ b_vb,
             const float* __restrict__ Mi0, const float* __restrict__ Mr0,
             const float* __restrict__ p_ib, const float* __restrict__ p_fb,
             const float* __restrict__ p_a1, const float* __restrict__ p_a2,
             float* __restrict__ tvec_all)
{
    const int tid = threadIdx.x;
    const int b = blockIdx.x;
    const int wv = tid >> 6;
    const int ln = tid & 63;
    const int g  = ln >> 4;
    const int li = ln & 15;

    __shared__ __align__(16) float Mi_s[S_ * 68];
    __shared__ __align__(16) _Float16 AsT[S_ * S_];
    __shared__ __align__(16) _Float16 AsX[S_ * S_];
    __shared__ __align__(16) _Float16 Mif16[S_ * S_];
    __shared__ __align__(16) _Float16 P_op[16 * S_];
    __shared__ __align__(16) _Float16 WmgT[2 * S_ * S_];
    __shared__ __align__(16) _Float16 WvbT[S_ * S_];
    __shared__ __align__(16) _Float16 WrelT[S_ * S_];
    __shared__ __align__(16) _Float16 WqkvT[16 * S_];
    __shared__ __align__(16) float vgT[12 * 68];
    __shared__ __align__(16) float gT[12 * 68];
    __shared__ __align__(16) float lbT[12 * 68];
    __shared__ __align__(16) float vvsT[S_ * 4];
    __shared__ __align__(16) float wvm[N_][S_];
    __shared__ __align__(16) float G2s[N_][S_];
    __shared__ __align__(16) float B2s[N_][S_];
    __shared__ __align__(16) float wavepart[16][S_];
    __shared__ float bmgin[128];
    __shared__ float b_mg_s[128];
    __shared__ __align__(16) float b_vb_s[64];
    __shared__ float b_qkv_s[16];
    __shared__ float vt[S_];
    __shared__ __align__(16) float w3s4[4];
    __shared__ __align__(16) float Amat[N_][N_];
    __shared__ __align__(16) float red1[16], red2[16];

    const float ib = p_ib[0], fb = p_fb[0], a1 = p_a1[0], a2v = p_a2[0];

    #define MI(r, c) Mi_s[(r) * 68 + (c)]

    for (int i = tid; i < 2 * S_ * S_; i += 1024) {
        int k = i >> 7, j = i & 127;
        WmgT[sidx(j, k)] = (_Float16)Wmg[i];
    }
    for (int i = tid; i < S_ * S_; i += 1024) {
        int r = i >> 6, j = i & 63;
        WvbT[sidx(j, r)] = (_Float16)Wvb[i];
    }
    for (int i = tid; i < S_ * S_; i += 1024) {
        int s = i >> 6, r = i & 63;
        WrelT[sidx(r, s)] = (_Float16)Wrel[i];
    }
    if (tid < 16 * S_) {
        int c = tid >> 6, k = tid & 63;
        float w = (c < 12) ? Wqkv[k * 12 + c] : 0.f;
        WqkvT[sidx(c, k)] = (_Float16)w;
    }
    if (tid < 768) {
        int s = tid / 12, c = tid - s * 12;
        gT[c * 68 + s]  = ln_g[tid];
        lbT[c * 68 + s] = ln_b[tid];
    }
    if (tid < 128) b_mg_s[tid] = b_mg[tid];
    else if (tid < 192) b_vb_s[tid - 128] = b_vb[tid - 128];
    else if (tid < 208) b_qkv_s[tid - 192] = (tid - 192 < 12) ? b_qkv[tid - 192] : 0.f;
    if (tid < 1024) P_op[tid] = (_Float16)0.f;
    if (tid < 256) {
        const int m = tid >> 6, r = tid & 63;
        float g2 = 0.f, b2 = 0.f;
        for (int s = 0; s < S_; ++s) {
            float w = Wrel[s * R_ + r];
            g2 = fmaf(ln_g[s * 12 + 8 + m], w, g2);
            b2 = fmaf(ln_b[s * 12 + 8 + m], w, b2);
        }
        G2s[m][r] = g2;
        B2s[m][r] = a1 * b2;
    }
    for (int i = tid; i < S_ * S_; i += 1024) MI(i >> 6, i & 63) = Mi0[i];
    {
        const int row = tid >> 4, k0 = (tid & 15) << 2;
        const float* mp = Mi0 + (tid << 2);
        h4 t4;
        t4[0] = (_Float16)ftanh(mp[0]); t4[1] = (_Float16)ftanh(mp[1]);
        t4[2] = (_Float16)ftanh(mp[2]); t4[3] = (_Float16)ftanh(mp[3]);
        *(h4*)&AsT[sidx(row, k0)] = t4;
    }
    f4 mrs0, mrs1, mrs2, mrs3, a1brel4;
    {
        const int s0i = tid >> 4, r4i = (tid & 15) << 2;
        const float* mrp = Mr0 + s0i * 64 + r4i;
        mrs0 = *(const f4*)&mrp[0];
        mrs1 = *(const f4*)&mrp[4096];
        mrs2 = *(const f4*)&mrp[8192];
        mrs3 = *(const f4*)&mrp[12288];
        f4 br = *(const f4*)&b_rel[r4i];
        a1brel4 = a1 * br;
    }
    if (tid < 64) vt[tid] = v_all[b * S_ + tid];
    else if (tid < 68) w3s4[tid - 64] = w3_all[b * N_ + (tid - 64)];
    if (tid >= 128 && tid < 256)
        bmgin[tid - 128] = b_mg[tid - 128] + gIn_all[b * 2 * S_ + (tid - 128)];
    __syncthreads();

    for (int t = 0; t < T_; ++t) {
        const int f = t * B_ + b;

        float pf = 0.f;
        {
            const int fn = ((t + 1 < T_) ? t + 1 : t) * B_ + b;
            if (tid >= 512 && tid < 576) pf = v_all[fn * S_ + (tid - 512)];
            else if (tid >= 576 && tid < 580) pf = w3_all[fn * N_ + (tid - 576)];
            else if (tid >= 640 && tid < 768) pf = gIn_all[fn * 2 * S_ + (tid - 640)];
        }
        {
            const int rowbase = (wv & 3) << 4;
            const int arow = rowbase + li;
            const int colI = ((wv >> 2) << 4) + li;
            const int colF = colI + 64;
            h8 af0 = *(const h8*)&AsT[fidx(arow, 0, g)];
            h8 af1 = *(const h8*)&AsT[fidx(arow, 1, g)];
            const float bi = bmgin[colI], bfv = bmgin[colF];
            f4 accI = {bi, bi, bi, bi};
            f4 accF = {bfv, bfv, bfv, bfv};
            accI = __builtin_amdgcn_mfma_f32_16x16x32_f16(af0, *(const h8*)&WmgT[fidx(colI, 0, g)], accI, 0, 0, 0);
            accI = __builtin_amdgcn_mfma_f32_16x16x32_f16(af1, *(const h8*)&WmgT[fidx(colI, 1, g)], accI, 0, 0, 0);
            accF = __builtin_amdgcn_mfma_f32_16x16x32_f16(af0, *(const h8*)&WmgT[fidx(colF, 0, g)], accF, 0, 0, 0);
            accF = __builtin_amdgcn_mfma_f32_16x16x32_f16(af1, *(const h8*)&WmgT[fidx(colF, 1, g)], accF, 0, 0, 0);
            const float vc = vt[colI];
#pragma unroll
            for (int r = 0; r < 4; ++r) {
                const int row = rowbase + (g << 2) + r;
                const float gi = fsigm(accI[r] + ib);
                const float gf = fsigm(accF[r] + fb);
                const float mo = MI(row, colI);
                const float mn = gf * mo + gi * ftanh(vt[row] * vc);
                MI(row, colI) = mn;
                Mif16[sidx(row, colI)] = (_Float16)mn;
            }
        }
        __syncthreads();

        if (wv < 4) {
            const int rowbase = wv << 4;
            const int arow = rowbase + li;
            h8 af0 = *(const h8*)&Mif16[fidx(arow, 0, g)];
            h8 af1 = *(const h8*)&Mif16[fidx(arow, 1, g)];
            const float bq = b_qkv_s[li];
            f4 qacc = {bq, bq, bq, bq};
            qacc = __builtin_amdgcn_mfma_f32_16x16x32_f16(af0, *(const h8*)&WqkvT[fidx(li, 0, g)], qacc, 0, 0, 0);
            qacc = __builtin_amdgcn_mfma_f32_16x16x32_f16(af1, *(const h8*)&WqkvT[fidx(li, 1, g)], qacc, 0, 0, 0);
            float s1 = 0.f, s2 = 0.f;
            if (li < 12) {
                const int srow = rowbase + (g << 2);
                f4 g4 = *(const f4*)&gT[li * 68 + srow];
                f4 vg = qacc * g4;
                *(f4*)&vgT[li * 68 + srow] = vg;
                s1 = (qacc[0] + qacc[1]) + (qacc[2] + qacc[3]);
                f4 sq = qacc * qacc;
                s2 = (sq[0] + sq[1]) + (sq[2] + sq[3]);
                if (li >= 8) {
                    h4 p4 = __builtin_convertvector(vg, h4);
                    *(h4*)&P_op[sidx(li - 8, srow)] = p4;
                }
            }
#pragma unroll
            for (int off = 8; off; off >>= 1) {
                s1 += __shfl_down(s1, off); s2 += __shfl_down(s2, off);
            }
            if (li == 0) { red1[(wv << 2) + g] = s1; red2[(wv << 2) + g] = s2; }
        }
        __syncthreads();

        {
            f4 rA = *(const f4*)&red1[0];
            rA += *(const f4*)&red1[4];
            rA += *(const f4*)&red1[8];
            rA += *(const f4*)&red1[12];
            f4 rB = *(const f4*)&red2[0];
            rB += *(const f4*)&red2[4];
            rB += *(const f4*)&red2[8];
            rB += *(const f4*)&red2[12];
            const float sA = (rA[0] + rA[1]) + (rA[2] + rA[3]);
            const float sB = (rB[0] + rB[1]) + (rB[2] + rB[3]);
            const float mu = sA * (1.f / 768.f);
            const float var = sB * (1.f / 768.f) - mu * mu;
            const float rstd = rsqrtf(var + 1e-5f);
            const float murstd = mu * rstd;
            if (wv < 4) {
                h8 af0 = *(const h8*)&P_op[fidx(li, 0, g)];
                h8 af1 = *(const h8*)&P_op[fidx(li, 1, g)];
                const int col = (wv << 4) + li;
                f4 acc = {0.f, 0.f, 0.f, 0.f};
                acc = __builtin_amdgcn_mfma_f32_16x16x32_f16(af0, *(const h8*)&WrelT[fidx(col, 0, g)], acc, 0, 0, 0);
                acc = __builtin_amdgcn_mfma_f32_16x16x32_f16(af1, *(const h8*)&WrelT[fidx(col, 1, g)], acc, 0, 0, 0);
                if (ln < 16) {
                    const float sa = a1 * rstd;
                    const float sb = -a1 * murstd;
#pragma unroll
                    for (int r = 0; r < 4; ++r)
                        wvm[r][col] = sa * acc[r] + sb * G2s[r][col] + B2s[r][col];
                }
            } else if (wv < 8) {
                const int n = wv - 4;
                const int s0 = li << 2;
                f4 vgq = *(const f4*)&vgT[n * 68 + s0];
                f4 gq  = *(const f4*)&gT [n * 68 + s0];
                f4 lbq = *(const f4*)&lbT[n * 68 + s0];
                f4 qv  = rstd * vgq - murstd * gq + lbq;
                const int kr = 4 + g;
                f4 vgk = *(const f4*)&vgT[kr * 68 + s0];
                f4 gk  = *(const f4*)&gT [kr * 68 + s0];
                f4 lbk = *(const f4*)&lbT[kr * 68 + s0];
                f4 kv  = rstd * vgk - murstd * gk + lbk;
                f4 pr = qv * kv;
                float a = (pr[0] + pr[1]) + (pr[2] + pr[3]);
                a += __shfl_down(a, 8);
                a += __shfl_down(a, 4);
                a += __shfl_down(a, 2);
                a += __shfl_down(a, 1);
                a *= 0.125f;
                float s0v = __shfl(a, 0), s1v = __shfl(a, 16);
                float s2v = __shfl(a, 32), s3v = __shfl(a, 48);
                if (li == 0) {
                    float mx = fmaxf(fmaxf(s0v, s1v), fmaxf(s2v, s3v));
                    float e0 = __expf(s0v - mx), e1 = __expf(s1v - mx);
                    float e2 = __expf(s2v - mx), e3 = __expf(s3v - mx);
                    float inv = __fdividef(1.f, e0 + e1 + e2 + e3);
                    float ev = (g == 0) ? e0 : (g == 1) ? e1 : (g == 2) ? e2 : e3;
                    Amat[n][g] = ev * inv;
                }
            } else if (wv < 12) {
                const int m = wv - 8;
                const int c = (8 + m) * 68 + ln;
                vvsT[(ln << 2) + m] = rstd * vgT[c] - murstd * gT[c] + lbT[c];
            }
        }
        __syncthreads();

        {
            const int s = tid >> 4, rq = tid & 15, r4 = rq << 2;
            f4 Am0 = *(const f4*)&Amat[0][0];
            f4 Am1 = *(const f4*)&Amat[1][0];
            f4 Am2 = *(const f4*)&Amat[2][0];
            f4 Am3 = *(const f4*)&Amat[3][0];
            f4 w3r = *(const f4*)&w3s4[0];
            f4 vv4 = *(const f4*)&vvsT[s << 2];
            f4 wvA4 = *(const f4*)&wvm[0][r4];
            f4 wvB4 = *(const f4*)&wvm[1][r4];
            f4 wvC4 = *(const f4*)&wvm[2][r4];
            f4 wvD4 = *(const f4*)&wvm[3][r4];
            {
                const float c0 = Am0[0] * vv4[0], c1 = Am0[1] * vv4[1];
                const float c2 = Am0[2] * vv4[2], c3 = Am0[3] * vv4[3];
                mrs0 += a1brel4 + c0 * wvA4 + c1 * wvB4 + c2 * wvC4 + c3 * wvD4;
            }
            {
                const float c0 = Am1[0] * vv4[0], c1 = Am1[1] * vv4[1];
                const float c2 = Am1[2] * vv4[2], c3 = Am1[3] * vv4[3];
                mrs1 += a1brel4 + c0 * wvA4 + c1 * wvB4 + c2 * wvC4 + c3 * wvD4;
            }
            {
                const float c0 = Am2[0] * vv4[0], c1 = Am2[1] * vv4[1];
                const float c2 = Am2[2] * vv4[2], c3 = Am2[3] * vv4[3];
                mrs2 += a1brel4 + c0 * wvA4 + c1 * wvB4 + c2 * wvC4 + c3 * wvD4;
            }
            {
                const float c0 = Am3[0] * vv4[0], c1 = Am3[1] * vv4[1];
                const float c2 = Am3[2] * vv4[2], c3 = Am3[3] * vv4[3];
                mrs3 += a1brel4 + c0 * wvA4 + c1 * wvB4 + c2 * wvC4 + c3 * wvD4;
            }
            f4 trv = w3r[0] * mrs0 + w3r[1] * mrs1 + w3r[2] * mrs2 + w3r[3] * mrs3;
            h4 trh = __builtin_convertvector(trv, h4);
            *(h4*)&AsX[sidx(s, r4)] = trh;
            f4 tp = vt[s] * trv;
            {
                f4 o;
                o[0] = __shfl_xor(tp[0], 16); o[1] = __shfl_xor(tp[1], 16);
                o[2] = __shfl_xor(tp[2], 16); o[3] = __shfl_xor(tp[3], 16);
                tp += o;
                o[0] = __shfl_xor(tp[0], 32); o[1] = __shfl_xor(tp[1], 32);
                o[2] = __shfl_xor(tp[2], 32); o[3] = __shfl_xor(tp[3], 32);
                tp += o;
            }
            if (ln < 16) *(f4*)&wavepart[wv][r4] = tp;
        }
        __syncthreads();

        {
            const int rowbase = (wv & 3) << 4;
            const int arow = rowbase + li;
            const int col = ((wv >> 2) << 4) + li;
            h8 af0 = *(const h8*)&AsX[fidx(arow, 0, g)];
            h8 af1 = *(const h8*)&AsX[fidx(arow, 1, g)];
            const float bv = b_vb_s[col];
            f4 acc = {bv, bv, bv, bv};
            acc = __builtin_amdgcn_mfma_f32_16x16x32_f16(af0, *(const h8*)&WvbT[fidx(col, 0, g)], acc, 0, 0, 0);
            acc = __builtin_amdgcn_mfma_f32_16x16x32_f16(af1, *(const h8*)&WvbT[fidx(col, 1, g)], acc, 0, 0, 0);
#pragma unroll
            for (int r = 0; r < 4; ++r) {
                const int row = rowbase + (g << 2) + r;
                const float mn = MI(row, col) + a2v * ftanh(acc[r]);
                MI(row, col) = mn;
                AsT[sidx(row, col)] = (_Float16)ftanh(mn);
            }
        }
        if (wv == 15) {
            float tv = 0.f;
#pragma unroll
            for (int w = 0; w < 16; ++w) tv += wavepart[w][ln];
            tvec_all[f * S_ + ln] = tv;
        } else if (tid >= 512 && tid < 768) {
            if (tid < 576) vt[tid - 512] = pf;
            else if (tid < 580) w3s4[tid - 576] = pf;
            else if (tid >= 640) bmgin[tid - 640] = b_mg_s[tid - 640] + pf;
        }
        __syncthreads();
    }
    #undef MI
}

// ---------------------------------------------------------------------------
// K3: MFMA post-pass — unchanged
// ---------------------------------------------------------------------------
__global__ __launch_bounds__(512)
void k3_post(const float* __restrict__ tvec_all, const float* __restrict__ xo_all,
             const _Float16* __restrict__ hW,
             const float* __restrict__ b_rel3, const float* __restrict__ b_m1,
             const float* __restrict__ b_m2, const float* __restrict__ b_out,
             const float* __restrict__ fc_g, const float* __restrict__ fc_b,
             const float* __restrict__ b_fc, float* __restrict__ out)
{
    __shared__ __align__(16) _Float16 afA[16 * 512];
    __shared__ __align__(16) _Float16 afB[16 * 512];
    __shared__ __align__(16) _Float16 afT[16 * 64];
    __shared__ __align__(16) _Float16 afO[16 * 64];
    __shared__ __align__(16) float ybuf[16 * 512];
    __shared__ float mus[16], rsts[16];
    const int tid = threadIdx.x;
    const int wv = tid >> 6, l = tid & 63, li = l & 15, g = l >> 4;
    const int f0 = blockIdx.x * 16;

    const _Float16* Wrel3F = hW + OFF_WREL3;
    const _Float16* Wm1F   = hW + OFF_WM1;
    const _Float16* Wm2F   = hW + OFF_WM2;
    const _Float16* WoutF  = hW + OFF_WOUT;
    const _Float16* WfcF   = hW + OFF_WFC;

    for (int i = tid; i < 16 * 64; i += 512) {
        int row = i >> 6, k = i & 63;
        afT[afw64(row, k)] = (_Float16)tvec_all[(f0 + row) * O_ + k];
    }
    __syncthreads();

    if (wv < 4) {
        h8 t0 = *(const h8*)&afT[afi64(li, 0, g)];
        h8 t1 = *(const h8*)&afT[afi64(li, 1, g)];
        const int col = (wv << 4) + li;
        const float bb = b_rel3[col];
        f4 acc = {bb, bb, bb, bb};
        acc = __builtin_amdgcn_mfma_f32_16x16x32_f16(
            t0, *(const h8*)&Wrel3F[((0 * 4 + wv) * 64 + l) * 8], acc, 0, 0, 0);
        acc = __builtin_amdgcn_mfma_f32_16x16x32_f16(
            t1, *(const h8*)&Wrel3F[((1 * 4 + wv) * 64 + l) * 8], acc, 0, 0, 0);
#pragma unroll
        for (int r = 0; r < 4; ++r) {
            const int row = (g << 2) + r;
            const float o = acc[r] + xo_all[(f0 + row) * O_ + col];
            afO[afw64(row, col)] = (_Float16)o;
        }
    }
    __syncthreads();

    {
        h8 o0 = *(const h8*)&afO[afi64(li, 0, g)];
        h8 o1 = *(const h8*)&afO[afi64(li, 1, g)];
#pragma unroll
        for (int c4 = 0; c4 < 4; ++c4) {
            const int ct = (wv << 2) + c4;
            const int col = (ct << 4) + li;
            const float bb = b_m1[col];
            f4 acc = {bb, bb, bb, bb};
            acc = __builtin_amdgcn_mfma_f32_16x16x32_f16(
                o0, *(const h8*)&Wm1F[((0 * 32 + ct) * 64 + l) * 8], acc, 0, 0, 0);
            acc = __builtin_amdgcn_mfma_f32_16x16x32_f16(
                o1, *(const h8*)&Wm1F[((1 * 32 + ct) * 64 + l) * 8], acc, 0, 0, 0);
#pragma unroll
            for (int r = 0; r < 4; ++r)
                afA[afw512((g << 2) + r, col)] = (_Float16)fmaxf(acc[r], 0.f);
        }
    }
    __syncthreads();

    {
        h8 a[16];
#pragma unroll
        for (int ks = 0; ks < 16; ++ks) a[ks] = *(const h8*)&afA[afi512(li, ks, g)];
#pragma unroll
        for (int c4 = 0; c4 < 4; ++c4) {
            const int ct = (wv << 2) + c4;
            const int col = (ct << 4) + li;
            const float bb = b_m2[col];
            f4 acc = {bb, bb, bb, bb};
#pragma unroll
            for (int ks = 0; ks < 16; ++ks)
                acc = __builtin_amdgcn_mfma_f32_16x16x32_f16(
                    a[ks], *(const h8*)&Wm2F[((ks * 32 + ct) * 64 + l) * 8], acc, 0, 0, 0);
#pragma unroll
            for (int r = 0; r < 4; ++r)
                afB[afw512((g << 2) + r, col)] = (_Float16)fmaxf(acc[r], 0.f);
        }
    }
    __syncthreads();

    {
        h8 a[16];
#pragma unroll
        for (int ks = 0; ks < 16; ++ks) a[ks] = *(const h8*)&afB[afi512(li, ks, g)];
#pragma unroll
        for (int c4 = 0; c4 < 4; ++c4) {
            const int ct = (wv << 2) + c4;
            const int col = (ct << 4) + li;
            const float bb = b_out[col];
            f4 acc = {bb, bb, bb, bb};
#pragma unroll
            for (int ks = 0; ks < 16; ++ks)
                acc = __builtin_amdgcn_mfma_f32_16x16x32_f16(
                    a[ks], *(const h8*)&WoutF[((ks * 32 + ct) * 64 + l) * 8], acc, 0, 0, 0);
#pragma unroll
            for (int r = 0; r < 4; ++r)
                ybuf[((g << 2) + r) * 512 + col] = acc[r];
        }
    }
    __syncthreads();

    {
        const int r = tid >> 5, l32 = tid & 31;
        float s1 = 0.f, s2 = 0.f;
        for (int k = l32; k < 512; k += 32) {
            float y = ybuf[r * 512 + k];
            s1 += y; s2 += y * y;
        }
#pragma unroll
        for (int off = 16; off; off >>= 1) {
            s1 += __shfl_down(s1, off, 32);
            s2 += __shfl_down(s2, off, 32);
        }
        if (l32 == 0) {
            float mu = s1 * (1.f / 512.f);
            float var = s2 * (1.f / 512.f) - mu * mu;
            mus[r] = mu; rsts[r] = rsqrtf(var + 1e-5f);
        }
    }
    __syncthreads();
    for (int i = tid; i < 16 * 512; i += 512) {
        int row = i >> 9, col = i & 511;
        float yn = (ybuf[row * 512 + col] - mus[row]) * rsts[row] * fc_g[col] + fc_b[col];
        afA[afw512(row, col)] = (_Float16)fmaxf(yn, 0.f);
    }
    __syncthreads();

    {
        h8 a[16];
#pragma unroll
        for (int ks = 0; ks < 16; ++ks) a[ks] = *(const h8*)&afA[afi512(li, ks, g)];
        const int col = (wv << 4) + li;
        const float bb = b_fc[col];
        f4 acc = {bb, bb, bb, bb};
#pragma unroll
        for (int ks = 0; ks < 16; ++ks)
            acc = __builtin_amdgcn_mfma_f32_16x16x32_f16(
                a[ks], *(const h8*)&WfcF[((ks * 8 + wv) * 64 + l) * 8], acc, 0, 0, 0);
#pragma unroll
        for (int r = 0; r < 4; ++r) {
            const int row = (g << 2) + r;
            const int f = f0 + row, t = f >> 5, bo = f & 31;
            out[bo * (V_ * T_) + col * T_ + t] = acc[r];
        }
    }
}

// ---------------------------------------------------------------------------
extern "C" void kernel_launch(void* const* d_in, const int* in_sizes, int n_in,
                              void* d_out, int out_size, void* d_ws, size_t ws_size,
                              hipStream_t stream)
{
    (void)in_sizes; (void)n_in; (void)out_size; (void)ws_size;
    const int*   ids   = (const int*)  d_in[0];
    const float* emb   = (const float*)d_in[1];
    const float* We    = (const float*)d_in[2];
    const float* be    = (const float*)d_in[3];
    const float* Win   = (const float*)d_in[4];
    const float* b_in  = (const float*)d_in[5];
    const float* Win2  = (const float*)d_in[6];
    const float* b_in2 = (const float*)d_in[7];
    const float* Win3  = (const float*)d_in[8];
    const float* b_in3 = (const float*)d_in[9];
    const float* Wig   = (const float*)d_in[10];
    const float* b_ig  = (const float*)d_in[11];
    const float* Wmg   = (const float*)d_in[12];
    const float* b_mg  = (const float*)d_in[13];
    const float* ibp   = (const float*)d_in[14];
    const float* fbp   = (const float*)d_in[15];
    const float* Wqkv  = (const float*)d_in[16];
    const float* b_qkv = (const float*)d_in[17];
    const float* ln_g  = (const float*)d_in[18];
    const float* ln_b  = (const float*)d_in[19];
    const float* a1p   = (const float*)d_in[20];
    const float* a2p   = (const float*)d_in[21];
    const float* Wrel  = (const float*)d_in[22];
    const float* b_rel = (const float*)d_in[23];
    const float* Wvb   = (const float*)d_in[24];
    const float* b_vb  = (const float*)d_in[25];
    const float* Wrel3 = (const float*)d_in[26];
    const float* b_rel3= (const float*)d_in[27];
    const float* Wm1   = (const float*)d_in[28];
    const float* b_m1  = (const float*)d_in[29];
    const float* Wm2   = (const float*)d_in[30];
    const float* b_m2  = (const float*)d_in[31];
    const float* Wout  = (const float*)d_in[32];
    const float* b_out = (const float*)d_in[33];
    const float* Mi0   = (const float*)d_in[34];
    const float* Mr0   = (const float*)d_in[35];
    const float* fc_g  = (const float*)d_in[36];
    const float* fc_b  = (const float*)d_in[37];
    const float* Wfc   = (const float*)d_in[38];
    const float* b_fc  = (const float*)d_in[39];

    float* ws = (float*)d_ws;
    float* v_all    = ws;
    float* gIn_all  = v_all    + T_ * B_ * S_;
    float* w3_all   = gIn_all  + T_ * B_ * 2 * S_;
    float* xo_all   = w3_all   + T_ * B_ * N_;
    float* tvec_all = xo_all   + T_ * B_ * O_;
    _Float16* hW    = (_Float16*)(tvec_all + T_ * B_ * O_);

    k0_conv<<<dim3((HW_TOTAL + 255) / 256), dim3(256), 0, stream>>>(
        We, Win, Win2, Win3, Wig, Wrel3, Wm1, Wm2, Wout, Wfc, hW);

    k1_pre<<<dim3((T_ * B_) / 16), dim3(512), 0, stream>>>(
        ids, emb, hW, be, b_in, b_in2, b_in3, b_ig,
        v_all, gIn_all, w3_all, xo_all);

    k2_scan<<<dim3(B_), dim3(1024), 0, stream>>>(
        v_all, gIn_all, w3_all,
        Wmg, b_mg, Wqkv, b_qkv, ln_g, ln_b,
        Wrel, b_rel, Wvb, b_vb,
        Mi0, Mr0, ibp, fbp, a1p, a2p, tvec_all);

    k3_post<<<dim3((T_ * B_) / 16), dim3(512), 0, stream>>>(
        tvec_all, xo_all, hW, b_rel3, b_m1, b_m2, b_out, fc_g, fc_b, b_fc,
        (float*)d_out);
}